// Round 6
// baseline (112.617 us; speedup 1.0000x reference)
//
#include <hip/hip_runtime.h>
#include <hip/hip_bf16.h>

#define CIN 8
#define IMG 224
#define PS 16
#define HP 14
#define D_ 768
#define HID 128
#define MPT 196      // Hp*Wp
#define K_ 256       // PS*PS
#define WSIZE 196608 // D_*K_
#define NJ 197376    // WSIZE + D_

typedef __bf16 bf16x8 __attribute__((ext_vector_type(8)));
typedef float f32x4 __attribute__((ext_vector_type(4)));

static __device__ __forceinline__ ushort f2bf(float f) {
  union { float f; unsigned int u; } x; x.f = f;
  unsigned int r = x.u + 0x7fffu + ((x.u >> 16) & 1u);
  return (ushort)(r >> 16);
}

// async global -> LDS, 16B per lane. LDS base wave-uniform; global addr per-lane.
static __device__ __forceinline__ void gload16(const void* g, void* l) {
  __builtin_amdgcn_global_load_lds(
      (const __attribute__((address_space(1))) unsigned int*)(uintptr_t)g,
      (__attribute__((address_space(3))) unsigned int*)(uintptr_t)l, 16, 0, 0);
}

// ---------- k1: ht[i][c] = relu(ce @ fc1_w + b1), 4-way K-split per block
__global__ __launch_bounds__(512) void k1_fc1(const float* __restrict__ ce,
                                              const float* __restrict__ w1,
                                              const float* __restrict__ b1,
                                              float* __restrict__ ht) {
  __shared__ float sh[3][HID];
  int c = blockIdx.x;
  int t = threadIdx.x;
  int i = t & 127, ksp = t >> 7;
  const float* cev = ce + c * D_ + ksp * 192;
  const float* wp = w1 + (size_t)(ksp * 192) * HID + i;
  float acc = 0.f;
#pragma unroll 8
  for (int d = 0; d < 192; ++d) acc = fmaf(cev[d], wp[(size_t)d * HID], acc);
  if (ksp) sh[ksp - 1][i] = acc;
  __syncthreads();
  if (ksp == 0) {
    float s = b1[i] + acc + sh[0][i] + sh[1][i] + sh[2][i];
    ht[i * CIN + c] = fmaxf(s, 0.f);
  }
}

// ---------- k2: y = tanh(h@fc2_w + b2); scatter wts(bf16, [c][d*256+k]) + bias(fp32)
__global__ __launch_bounds__(256) void k2_fc2(
    const float* __restrict__ ht, const float* __restrict__ w2,
    const float* __restrict__ b2, ushort* __restrict__ wbf,
    float* __restrict__ biasOut) {
  int t = threadIdx.x;
  int j = blockIdx.x * 256 + t;
  const float* wp = w2 + j;
  const float4* ht4 = (const float4*)ht;  // uniform index -> scalar loads
  float4 a0 = {0, 0, 0, 0}, a1 = {0, 0, 0, 0};
#pragma unroll 8
  for (int i = 0; i < HID; ++i) {
    float wv = wp[(size_t)i * NJ];
    float4 hA = ht4[i * 2], hB = ht4[i * 2 + 1];
    a0.x = fmaf(hA.x, wv, a0.x); a0.y = fmaf(hA.y, wv, a0.y);
    a0.z = fmaf(hA.z, wv, a0.z); a0.w = fmaf(hA.w, wv, a0.w);
    a1.x = fmaf(hB.x, wv, a1.x); a1.y = fmaf(hB.y, wv, a1.y);
    a1.z = fmaf(hB.z, wv, a1.z); a1.w = fmaf(hB.w, wv, a1.w);
  }
  float bb = b2[j];
  if (j < WSIZE) {
    wbf[(size_t)0 * WSIZE + j] = f2bf(tanhf(a0.x + bb));
    wbf[(size_t)1 * WSIZE + j] = f2bf(tanhf(a0.y + bb));
    wbf[(size_t)2 * WSIZE + j] = f2bf(tanhf(a0.z + bb));
    wbf[(size_t)3 * WSIZE + j] = f2bf(tanhf(a0.w + bb));
    wbf[(size_t)4 * WSIZE + j] = f2bf(tanhf(a1.x + bb));
    wbf[(size_t)5 * WSIZE + j] = f2bf(tanhf(a1.y + bb));
    wbf[(size_t)6 * WSIZE + j] = f2bf(tanhf(a1.z + bb));
    wbf[(size_t)7 * WSIZE + j] = f2bf(tanhf(a1.w + bb));
  } else {
    int jb = j - WSIZE;
    biasOut[0 * D_ + jb] = tanhf(a0.x + bb);
    biasOut[1 * D_ + jb] = tanhf(a0.y + bb);
    biasOut[2 * D_ + jb] = tanhf(a0.z + bb);
    biasOut[3 * D_ + jb] = tanhf(a0.w + bb);
    biasOut[4 * D_ + jb] = tanhf(a1.x + bb);
    biasOut[5 * D_ + jb] = tanhf(a1.y + bb);
    biasOut[6 * D_ + jb] = tanhf(a1.z + bb);
    biasOut[7 * D_ + jb] = tanhf(a1.w + bb);
  }
}

// ---------- k3: per-channel GEMM, 128x128 tile, BK=32 x 8 steps, m97-style.
// BOTH operands staged via global_load_lds (pure DMA, no staging VALU):
//   A staged as FP32 straight from x (16KB/step), fp32->bf16 cvt AFTER ds_read (in regs).
//   B staged as bf16 from wbf (8KB/step).
// Double-buffered; loads for ks+1 issued right after the barrier -> land during compute.
// Swizzles (rule 21, both-sides): A 16B-part p_phys = p ^ (row&7); B p_phys = p ^ (row&3).
__global__ __launch_bounds__(256, 3) void k3_gemm(
    const float* __restrict__ x, const ushort* __restrict__ wbf,
    const float* __restrict__ bias, float* __restrict__ out) {
  __shared__ float  As[2][128 * 32];   // 2 x 16KB fp32
  __shared__ ushort Bs[2][128 * 32];   // 2 x 8KB  bf16

  int bid = blockIdx.x;
  int c = bid & 7;            // channel == XCD (HW round-robin): x slice + weights L2-local
  int rem = bid >> 3;
  int mt = rem / 6;
  int nt = rem - mt * 6;      // 6 siblings share A rows within one XCD
  int m0 = mt * 128, n0 = nt * 128;

  int t = threadIdx.x;
  int lane = t & 63;
  int w = t >> 6;
  int wr = w >> 1, wc = w & 1;   // 2x2 wave grid, 64x64 per wave
  int rB = lane & 15;
  int h = lane >> 4;

  const ushort* wsrc = wbf + (size_t)c * WSIZE + (size_t)n0 * K_;

  // ---- A staging sources: 4 chunks/thread/step (chunk idx = i*256+t; row=idx>>3, p'=t&7)
  // logical part p = p' ^ (row&7); row&7 == (t>>3)&7 for all i -> p identical per thread
  int pA = (t & 7) ^ ((t >> 3) & 7);
  int prow = pA >> 2, qA = pA & 3;        // image-row within step, 16B quarter
  const float* asrc[4];
#pragma unroll
  for (int i = 0; i < 4; ++i) {
    int row = i * 32 + (t >> 3);
    int m = m0 + row;
    int b = m / MPT;
    int hw = m - b * MPT;
    int hp = hw / HP;
    int wp = hw - hp * HP;
    asrc[i] = x + ((size_t)(b * CIN + c) * IMG + hp * PS) * IMG + wp * PS
            + prow * IMG + qA * 4;
  }
  // ---- B staging sources: 2 chunks/thread/step (idx = j*256+t; row=idx>>2, p'=t&3)
  int pB = (t & 3) ^ ((t >> 2) & 3);
  const ushort* bsrc[2];
#pragma unroll
  for (int j = 0; j < 2; ++j)
    bsrc[j] = wsrc + ((t >> 2) + j * 64) * K_ + pB * 8;

#define K3_ISSUE(ks, buf)                                                    \
  {                                                                          \
    _Pragma("unroll") for (int i = 0; i < 4; ++i)                            \
        gload16(asrc[i] + (ks) * 2 * IMG, &As[buf][(i * 256 + w * 64) * 4]); \
    _Pragma("unroll") for (int j = 0; j < 2; ++j)                            \
        gload16(bsrc[j] + (ks) * 32, &Bs[buf][(j * 256 + w * 64) * 8]);      \
  }

  // ---- prologue
  K3_ISSUE(0, 0);

  f32x4 acc[4][4] = {};

#pragma unroll
  for (int ks = 0; ks < 8; ++ks) {
    __syncthreads();                 // drains vmcnt -> buf[ks&1] ready; other buf free
    if (ks < 7) K3_ISSUE(ks + 1, (ks + 1) & 1);   // pure DMA, lands during compute
    const float*  Ab = As[ks & 1];
    const ushort* Bb = Bs[ks & 1];
    bf16x8 af[4], bq[4];
#pragma unroll
    for (int mi = 0; mi < 4; ++mi) {
      int r = wr * 64 + mi * 16 + rB;
      int s7 = r & 7;
      f32x4 lo = *(const f32x4*)&Ab[r * 32 + (((h * 2)     ^ s7) * 4)];
      f32x4 hi = *(const f32x4*)&Ab[r * 32 + (((h * 2 + 1) ^ s7) * 4)];
      union { __bf16 e[8]; bf16x8 v; } u;
      u.e[0] = (__bf16)lo[0]; u.e[1] = (__bf16)lo[1];
      u.e[2] = (__bf16)lo[2]; u.e[3] = (__bf16)lo[3];
      u.e[4] = (__bf16)hi[0]; u.e[5] = (__bf16)hi[1];
      u.e[6] = (__bf16)hi[2]; u.e[7] = (__bf16)hi[3];
      af[mi] = u.v;
    }
#pragma unroll
    for (int ni = 0; ni < 4; ++ni) {
      int r = wc * 64 + ni * 16 + rB;
      bq[ni] = *(const bf16x8*)&Bb[r * 32 + ((h ^ (r & 3)) * 8)];
    }
#pragma unroll
    for (int mi = 0; mi < 4; ++mi)
#pragma unroll
      for (int ni = 0; ni < 4; ++ni)
        acc[mi][ni] = __builtin_amdgcn_mfma_f32_16x16x32_bf16(af[mi], bq[ni], acc[mi][ni], 0, 0, 0);
  }

  // ---- epilogue: + bias.  C/D: col = lane&15, row = (lane>>4)*4 + reg
  float bv[4];
#pragma unroll
  for (int ni = 0; ni < 4; ++ni)
    bv[ni] = bias[c * D_ + n0 + wc * 64 + ni * 16 + rB];
#pragma unroll
  for (int mi = 0; mi < 4; ++mi) {
#pragma unroll
    for (int r = 0; r < 4; ++r) {
      int mrow = m0 + wr * 64 + mi * 16 + h * 4 + r;
      int b2 = mrow / MPT;
      int hw2 = mrow - b2 * MPT;
      float* op = out + ((size_t)b2 * (CIN * MPT) + c * MPT + hw2) * D_ + n0 + wc * 64 + rB;
#pragma unroll
      for (int ni = 0; ni < 4; ++ni)
        op[ni * 16] = acc[mi][ni][r] + bv[ni];
    }
  }
}

extern "C" void kernel_launch(void* const* d_in, const int* in_sizes, int n_in,
                              void* d_out, int out_size, void* d_ws, size_t ws_size,
                              hipStream_t stream) {
  const float* x  = (const float*)d_in[0];
  const float* ce = (const float*)d_in[2];
  const float* w1 = (const float*)d_in[3];
  const float* b1 = (const float*)d_in[4];
  const float* w2 = (const float*)d_in[5];
  const float* b2 = (const float*)d_in[6];
  float* out = (float*)d_out;

  char* ws = (char*)d_ws;
  float*  ht      = (float*)ws;                    // 128*8*4   = 4096 B  (transposed h)
  float*  biasOut = (float*)(ws + 4096);           // 8*768*4   = 24576 B
  ushort* wbf     = (ushort*)(ws + 4096 + 24576);  // 8*196608*2 = 3145728 B

  k1_fc1<<<dim3(CIN), dim3(512), 0, stream>>>(ce, w1, b1, ht);
  k2_fc2<<<dim3(NJ / 256), dim3(256), 0, stream>>>(ht, w2, b2, wbf, biasOut);
  k3_gemm<<<dim3(8 * 49 * 6), dim3(256), 0, stream>>>(x, wbf, biasOut, out);
}

// Round 7
// 99.909 us; speedup vs baseline: 1.1272x; 1.1272x over previous
//
#include <hip/hip_runtime.h>
#include <hip/hip_bf16.h>

#define CIN 8
#define IMG 224
#define PS 16
#define HP 14
#define D_ 768
#define HID 128
#define MPT 196      // Hp*Wp
#define K_ 256       // PS*PS
#define WSIZE 196608 // D_*K_
#define NJ 197376    // WSIZE + D_
#define XN (32 * CIN * IMG * IMG)  // 12,845,056 x elements

typedef __bf16 bf16x8 __attribute__((ext_vector_type(8)));
typedef float f32x4 __attribute__((ext_vector_type(4)));

static __device__ __forceinline__ ushort f2bf(float f) {
  union { float f; unsigned int u; } x; x.f = f;
  unsigned int r = x.u + 0x7fffu + ((x.u >> 16) & 1u);
  return (ushort)(r >> 16);
}

// async global -> LDS, 16B per lane. LDS base wave-uniform; global addr per-lane.
static __device__ __forceinline__ void gload16(const void* g, void* l) {
  __builtin_amdgcn_global_load_lds(
      (const __attribute__((address_space(1))) unsigned int*)(uintptr_t)g,
      (__attribute__((address_space(3))) unsigned int*)(uintptr_t)l, 16, 0, 0);
}

// ---------- k1: ht[i][c] = relu(ce @ fc1_w + b1), 4-way K-split per block
__global__ __launch_bounds__(512) void k1_fc1(const float* __restrict__ ce,
                                              const float* __restrict__ w1,
                                              const float* __restrict__ b1,
                                              float* __restrict__ ht) {
  __shared__ float sh[3][HID];
  int c = blockIdx.x;
  int t = threadIdx.x;
  int i = t & 127, ksp = t >> 7;
  const float* cev = ce + c * D_ + ksp * 192;
  const float* wp = w1 + (size_t)(ksp * 192) * HID + i;
  float acc = 0.f;
#pragma unroll 8
  for (int d = 0; d < 192; ++d) acc = fmaf(cev[d], wp[(size_t)d * HID], acc);
  if (ksp) sh[ksp - 1][i] = acc;
  __syncthreads();
  if (ksp == 0) {
    float s = b1[i] + acc + sh[0][i] + sh[1][i] + sh[2][i];
    ht[i * CIN + c] = fmaxf(s, 0.f);
  }
}

// ---------- k2 fused: {y = tanh(h@fc2_w + b2) scatter} + {x fp32 -> bf16 convert}
__global__ __launch_bounds__(256) void k2_fused(
    const float* __restrict__ ht, const float* __restrict__ w2,
    const float* __restrict__ b2, const float* __restrict__ x,
    ushort* __restrict__ wbf, float* __restrict__ biasOut,
    ushort* __restrict__ xbf, int nCol) {
  int bid = blockIdx.x;
  int t = threadIdx.x;
  if (bid >= nCol) {
    // ---- x -> bf16 (8 elements / thread / iter)
    int u = (bid - nCol) * 256 + t;
    int stride = (gridDim.x - nCol) * 256;
    const float4* xv = (const float4*)x;
    for (int v = u; v < XN / 8; v += stride) {
      float4 f0 = xv[v * 2], f1 = xv[v * 2 + 1];
      union { ushort s[8]; uint4 q; } pk;
      pk.s[0] = f2bf(f0.x); pk.s[1] = f2bf(f0.y); pk.s[2] = f2bf(f0.z); pk.s[3] = f2bf(f0.w);
      pk.s[4] = f2bf(f1.x); pk.s[5] = f2bf(f1.y); pk.s[6] = f2bf(f1.z); pk.s[7] = f2bf(f1.w);
      *(uint4*)(xbf + (size_t)v * 8) = pk.q;
    }
    return;
  }
  int j = bid * 256 + t;
  const float* wp = w2 + j;
  const float4* ht4 = (const float4*)ht;  // uniform index -> broadcast loads
  float4 a0 = {0, 0, 0, 0}, a1 = {0, 0, 0, 0};
#pragma unroll 8
  for (int i = 0; i < HID; ++i) {
    float wv = wp[(size_t)i * NJ];
    float4 hA = ht4[i * 2], hB = ht4[i * 2 + 1];
    a0.x = fmaf(hA.x, wv, a0.x); a0.y = fmaf(hA.y, wv, a0.y);
    a0.z = fmaf(hA.z, wv, a0.z); a0.w = fmaf(hA.w, wv, a0.w);
    a1.x = fmaf(hB.x, wv, a1.x); a1.y = fmaf(hB.y, wv, a1.y);
    a1.z = fmaf(hB.z, wv, a1.z); a1.w = fmaf(hB.w, wv, a1.w);
  }
  float bb = b2[j];
  if (j < WSIZE) {
    wbf[(size_t)0 * WSIZE + j] = f2bf(tanhf(a0.x + bb));
    wbf[(size_t)1 * WSIZE + j] = f2bf(tanhf(a0.y + bb));
    wbf[(size_t)2 * WSIZE + j] = f2bf(tanhf(a0.z + bb));
    wbf[(size_t)3 * WSIZE + j] = f2bf(tanhf(a0.w + bb));
    wbf[(size_t)4 * WSIZE + j] = f2bf(tanhf(a1.x + bb));
    wbf[(size_t)5 * WSIZE + j] = f2bf(tanhf(a1.y + bb));
    wbf[(size_t)6 * WSIZE + j] = f2bf(tanhf(a1.z + bb));
    wbf[(size_t)7 * WSIZE + j] = f2bf(tanhf(a1.w + bb));
  } else {
    int jb = j - WSIZE;
    biasOut[0 * D_ + jb] = tanhf(a0.x + bb);
    biasOut[1 * D_ + jb] = tanhf(a0.y + bb);
    biasOut[2 * D_ + jb] = tanhf(a0.z + bb);
    biasOut[3 * D_ + jb] = tanhf(a0.w + bb);
    biasOut[4 * D_ + jb] = tanhf(a1.x + bb);
    biasOut[5 * D_ + jb] = tanhf(a1.y + bb);
    biasOut[6 * D_ + jb] = tanhf(a1.z + bb);
    biasOut[7 * D_ + jb] = tanhf(a1.w + bb);
  }
}

// ---------- k3: per-channel GEMM, 128x128 tile, BK=32 x 8 steps.
// Both operands bf16, staged by PURE DMA (global_load_lds) into part-planed LDS:
//   tile[plane p][row][16B] with p = k-part (8 bf16). Chunk idx = p*128+row maps
//   linearly to gload16's lane-linear dest -> no swizzle needed anywhere.
// Fragment read: &plane[h][r*16B]: 16 lanes x consecutive rows = 256B contiguous
// -> conflict-free by construction. Per step/wave: 8 ds_read_b128 + 16 MFMA, 0 VALU.
__global__ __launch_bounds__(256, 4) void k3_gemm(
    const ushort* __restrict__ xbf, const ushort* __restrict__ wbf,
    const float* __restrict__ bias, float* __restrict__ out) {
  __shared__ ushort As[2][4096];   // 2 x 8KB: [p][row][8]
  __shared__ ushort Bs[2][4096];

  int bid = blockIdx.x;
  int c = bid & 7;            // channel == XCD: x slice (3.2MB bf16) + weights L2-local
  int rem = bid >> 3;
  int mt = rem / 6;
  int nt = rem - mt * 6;      // 6 siblings share A rows within one XCD
  int m0 = mt * 128, n0 = nt * 128;

  int t = threadIdx.x;
  int lane = t & 63;
  int w = t >> 6;
  int wr = w >> 1, wc = w & 1;   // 2x2 wave grid, 64x64 per wave
  int rB = lane & 15;
  int h = lane >> 4;

  // ---- staging sources. Thread t owns chunks {t, t+256}: both row = t&127,
  // parts p0 = t>>7 and p0+2. For A: part -> (krow = p>>1, kcol = (p&1)*8), so
  // chunk(t+256) = chunk(t) + IMG. For B: k-offset p*8 -> +16.
  int rowL = t & 127;
  int p0 = t >> 7;            // 0 or 1
  const ushort* aBase;
  {
    int m = m0 + rowL;
    int b = m / MPT;
    int hw = m - b * MPT;
    int hp = hw / HP;
    int wp = hw - hp * HP;
    aBase = xbf + ((size_t)(b * CIN + c) * IMG + hp * PS) * IMG + wp * PS + p0 * 8;
  }
  const ushort* bBase = wbf + (size_t)c * WSIZE + (size_t)(n0 + rowL) * K_ + p0 * 8;

#define K3_ISSUE(ks, buf)                                               \
  {                                                                     \
    gload16(aBase + (ks) * 2 * IMG,       &As[buf][(w * 64) * 8]);      \
    gload16(aBase + (ks) * 2 * IMG + IMG, &As[buf][(256 + w * 64) * 8]);\
    gload16(bBase + (ks) * 32,            &Bs[buf][(w * 64) * 8]);      \
    gload16(bBase + (ks) * 32 + 16,       &Bs[buf][(256 + w * 64) * 8]);\
  }

  K3_ISSUE(0, 0);

  f32x4 acc[4][4] = {};

#pragma unroll
  for (int ks = 0; ks < 8; ++ks) {
    __syncthreads();                 // buf[ks&1] ready (barrier drains vmcnt)
    if (ks < 7) K3_ISSUE(ks + 1, (ks + 1) & 1);   // pure DMA, lands during compute
    const ushort* Ab = As[ks & 1];
    const ushort* Bb = Bs[ks & 1];
    bf16x8 af[4], bq[4];
#pragma unroll
    for (int mi = 0; mi < 4; ++mi)
      af[mi] = *(const bf16x8*)&Ab[h * 1024 + (wr * 64 + mi * 16 + rB) * 8];
#pragma unroll
    for (int ni = 0; ni < 4; ++ni)
      bq[ni] = *(const bf16x8*)&Bb[h * 1024 + (wc * 64 + ni * 16 + rB) * 8];
#pragma unroll
    for (int mi = 0; mi < 4; ++mi)
#pragma unroll
      for (int ni = 0; ni < 4; ++ni)
        acc[mi][ni] = __builtin_amdgcn_mfma_f32_16x16x32_bf16(af[mi], bq[ni], acc[mi][ni], 0, 0, 0);
  }

  // ---- epilogue: + bias.  C/D: col = lane&15, row = (lane>>4)*4 + reg
  float bv[4];
#pragma unroll
  for (int ni = 0; ni < 4; ++ni)
    bv[ni] = bias[c * D_ + n0 + wc * 64 + ni * 16 + rB];
#pragma unroll
  for (int mi = 0; mi < 4; ++mi) {
#pragma unroll
    for (int r = 0; r < 4; ++r) {
      int mrow = m0 + wr * 64 + mi * 16 + h * 4 + r;
      int b2 = mrow / MPT;
      int hw2 = mrow - b2 * MPT;
      float* op = out + ((size_t)b2 * (CIN * MPT) + c * MPT + hw2) * D_ + n0 + wc * 64 + rB;
#pragma unroll
      for (int ni = 0; ni < 4; ++ni)
        op[ni * 16] = acc[mi][ni][r] + bv[ni];
    }
  }
}

extern "C" void kernel_launch(void* const* d_in, const int* in_sizes, int n_in,
                              void* d_out, int out_size, void* d_ws, size_t ws_size,
                              hipStream_t stream) {
  const float* x  = (const float*)d_in[0];
  const float* ce = (const float*)d_in[2];
  const float* w1 = (const float*)d_in[3];
  const float* b1 = (const float*)d_in[4];
  const float* w2 = (const float*)d_in[5];
  const float* b2 = (const float*)d_in[6];
  float* out = (float*)d_out;

  char* ws = (char*)d_ws;
  float*  ht      = (float*)ws;                    // 128*8*4   = 4096 B  (transposed h)
  float*  biasOut = (float*)(ws + 4096);           // 8*768*4   = 24576 B
  ushort* wbf     = (ushort*)(ws + 4096 + 24576);  // 8*196608*2 = 3145728 B
  ushort* xbf     = (ushort*)(ws + 4096 + 24576 + 3145728);  // XN*2 = 25690112 B

  int nCol = NJ / 256;                 // 771 exactly
  int nConv = 512;

  k1_fc1<<<dim3(CIN), dim3(512), 0, stream>>>(ce, w1, b1, ht);
  k2_fused<<<dim3(nCol + nConv), dim3(256), 0, stream>>>(ht, w2, b2, x, wbf, biasOut, xbf, nCol);
  k3_gemm<<<dim3(8 * 49 * 6), dim3(256), 0, stream>>>(xbf, wbf, biasOut, out);
}